// Round 2
// baseline (131.839 us; speedup 1.0000x reference)
//
#include <hip/hip_runtime.h>

#define Bn   4
#define CIN  32
#define COUT 32
#define CG   8
#define Hh   128
#define Ww   128
#define KK   5
#define HW   (Hh * Ww)
#define TS   16     // 16x16 pixel tile per block
#define PR   20     // patch region (TS + 4)
#define PSTR 24     // LDS row stride: 24 floats -> max 2-way bank aliasing (free)
#define JG   8      // x channels staged per group

// block = 256 threads = 16x16 pixel tile; blockIdx.y = output quarter (8 ch).
// x staged in LDS (zero-padded halo -> no bounds checks in inner loop).
// weight/bias indices are wave-uniform -> scalar loads (SGPR pipe).
__global__ __launch_bounds__(256, 4) void pac_lds(
    const float* __restrict__ x, const float* __restrict__ guide,
    const float* __restrict__ weight, const float* __restrict__ bias,
    float* __restrict__ out)
{
    __shared__ float sx[JG][PR * PSTR];   // 8 * 20*24 * 4B = 15.36 KB

    const int tid = threadIdx.x;
    const int tx = tid & (TS - 1), ty = tid >> 4;
    const int tile = blockIdx.x;              // 0..63
    const int quarter = blockIdx.y;           // 0..3
    const int b = blockIdx.z;
    const int tm = (tile >> 3) * TS, tn = (tile & 7) * TS;
    const int m = tm + ty, n = tn + tx;

    // ---- adaptive kernel from guide (global, bounds-checked, once) ----
    const float* gb = guide + ((size_t)b * CG) * HW + m * Ww + n;
    float center[CG];
#pragma unroll
    for (int c = 0; c < CG; ++c) center[c] = gb[c * HW];

    float kern[KK * KK];
#pragma unroll
    for (int k = 0; k < KK; ++k) {
        const int dm = k - 2;
        const bool rowok = ((unsigned)(m + dm) < (unsigned)Hh);
#pragma unroll
        for (int l = 0; l < KK; ++l) {
            const int dn = l - 2;
            const bool ok = rowok && ((unsigned)(n + dn) < (unsigned)Ww);
            float ss = 0.f;
#pragma unroll
            for (int c = 0; c < CG; ++c) {
                float gv = ok ? gb[c * HW + dm * Ww + dn] : 0.f;
                float d = gv - center[c];
                ss = fmaf(d, d, ss);
            }
            kern[k * KK + l] = __expf(-0.5f * ss);
        }
    }

    // ---- convolution: LDS-staged x, scalar-loaded weights ----
    float acc[8];
#pragma unroll
    for (int o = 0; o < 8; ++o) acc[o] = 0.f;

    const int obase = quarter * 8;
    const float* wq = weight + (size_t)obase * (CIN * KK * KK);
    const float* xb = x + ((size_t)b * CIN) * HW;

    for (int g = 0; g < CIN / JG; ++g) {
        if (g) __syncthreads();
        // stage JG channels of the 20x20 halo tile, zero-padded
        for (int idx = tid; idx < JG * PR * PR; idx += 256) {
            const int ch = idx / (PR * PR);
            const int rem = idx - ch * (PR * PR);
            const int r = rem / PR, c = rem - r * PR;
            const int gm = tm - 2 + r, gn = tn - 2 + c;
            float v = 0.f;
            if ((unsigned)gm < (unsigned)Hh && (unsigned)gn < (unsigned)Ww)
                v = xb[(size_t)(g * JG + ch) * HW + gm * Ww + gn];
            sx[ch][r * PSTR + c] = v;
        }
        __syncthreads();

#pragma unroll
        for (int jj = 0; jj < JG; ++jj) {
            float xv[KK * KK];
#pragma unroll
            for (int k = 0; k < KK; ++k)
#pragma unroll
                for (int l = 0; l < KK; ++l)
                    xv[k * KK + l] = sx[jj][(ty + k) * PSTR + tx + l] * kern[k * KK + l];

            const int j = g * JG + jj;
#pragma unroll
            for (int o = 0; o < 8; ++o) {
                const float* wo = wq + (size_t)o * (CIN * KK * KK) + j * (KK * KK);
                float a = acc[o];
#pragma unroll
                for (int t = 0; t < KK * KK; ++t)
                    a = fmaf(xv[t], wo[t], a);
                acc[o] = a;
            }
        }
    }

    float* op = out + ((size_t)b * COUT) * HW + m * Ww + n;
#pragma unroll
    for (int o = 0; o < 8; ++o)
        op[(size_t)(obase + o) * HW] = acc[o] + bias[obase + o];
}

extern "C" void kernel_launch(void* const* d_in, const int* in_sizes, int n_in,
                              void* d_out, int out_size, void* d_ws, size_t ws_size,
                              hipStream_t stream) {
    const float* x      = (const float*)d_in[0];
    const float* guide  = (const float*)d_in[1];
    const float* weight = (const float*)d_in[2];
    const float* bias   = (const float*)d_in[3];
    float* out = (float*)d_out;

    dim3 grid(64, 4, Bn);   // 64 tiles * 4 output-quarters * 4 batches = 1024 blocks
    pac_lds<<<grid, dim3(256), 0, stream>>>(x, guide, weight, bias, out);
}